// Round 3
// baseline (691.962 us; speedup 1.0000x reference)
//
#include <hip/hip_runtime.h>

// SynthesisBlock: style-modulated 3x3 conv, bf16 implicit-GEMM MFMA.
// d_ws layout: [0,16KB) style fp32[16][256]; [16KB,32KB) demod fp32[16][256];
// [32KB, +1.125MB) repacked bf16 weights wp, 16B-units [kh][cc][kw][g][m 256];
// [1212416, +128MB) xg: modulated bf16 input, per-(b,h,cc) 8KB blocks,
//   16B-unit slot = x*4 + ((g + ((x+1)>>1)) & 3)   (bank-swizzle, bijective).
//
// R3: conflict-free A layout (fragment lanes read contiguous 256B); X staged
// via async global_load_lds from precomputed xg (modulate+cvt hoisted to
// xprep_k); fallback template path (XG=0) if ws_size < ~130 MiB.

typedef __bf16 bf16;
typedef bf16 bf16x8 __attribute__((ext_vector_type(8)));
typedef bf16 bf16x4 __attribute__((ext_vector_type(4)));
typedef float f32x4 __attribute__((ext_vector_type(4)));

#define GLOBAL_AS __attribute__((address_space(1)))
#define LDS_AS __attribute__((address_space(3)))

// ---------------- prep: style[b][i] = latent[b]·aff_w[i]*sqrt(1/512) + aff_b[i]
__global__ __launch_bounds__(256) void style_k(const float* __restrict__ latent,
                                               const float* __restrict__ aff_w,
                                               const float* __restrict__ aff_b,
                                               float* __restrict__ style) {
  const int wid = blockIdx.x * 4 + (threadIdx.x >> 6);  // 0..4095
  const int lane = threadIdx.x & 63;
  const int b = wid >> 8, i = wid & 255;
  float acc = 0.f;
#pragma unroll
  for (int k = 0; k < 8; ++k) {
    const int l = lane + 64 * k;
    acc += latent[b * 512 + l] * aff_w[i * 512 + l];
  }
#pragma unroll
  for (int off = 32; off > 0; off >>= 1) acc += __shfl_xor(acc, off, 64);
  if (lane == 0) style[b * 256 + i] = acc * 0.04419417382415922f + aff_b[i];
}

// ---------------- prep: demod[b][o] = rsqrt(sum_i wsq[o][i]*style[b][i]^2 + 1e-8)
__global__ __launch_bounds__(256) void demod_k(const float* __restrict__ conv_w,
                                               const float* __restrict__ style,
                                               float* __restrict__ demod) {
  __shared__ float s_wsq[256];
  const int o = blockIdx.x, i = threadIdx.x;
  float wsq = 0.f;
#pragma unroll
  for (int t = 0; t < 9; ++t) {
    const float w = conv_w[(o * 256 + i) * 9 + t];
    wsq += w * w;
  }
  s_wsq[i] = wsq;
  __syncthreads();
  const int wv = threadIdx.x >> 6, lane = threadIdx.x & 63;
  for (int b = wv; b < 16; b += 4) {
    float p = 0.f;
#pragma unroll
    for (int k = 0; k < 4; ++k) {
      const int ii = lane + 64 * k;
      const float s = style[b * 256 + ii];
      p += s_wsq[ii] * s * s;
    }
#pragma unroll
    for (int off = 32; off > 0; off >>= 1) p += __shfl_xor(p, off, 64);
    if (lane == 0) demod[b * 256 + o] = rsqrtf(p + 1e-8f);
  }
}

// ---------------- prep: conv_w fp32[o][c][kh][kw] -> bf16 wp 16B-units [kh][cc][kw][g][m]
__global__ __launch_bounds__(256) void wprep_k(const float* __restrict__ conv_w,
                                               bf16* __restrict__ wp) {
  const int idx = blockIdx.x * 256 + threadIdx.x;  // < 589824
  const int e = idx & 7;
  const int m = (idx >> 3) & 255;
  const int g = (idx >> 11) & 3;
  const int rest = idx >> 13;
  const int kw = rest % 3;
  const int t = rest / 3;
  const int cc = t & 7, kh = t >> 3;
  wp[idx] = (bf16)conv_w[((m * 256 + cc * 32 + g * 8 + e) * 3 + kh) * 3 + kw];
}

// ---------------- prep: xg[b][h][cc] 8KB block = modulated bf16, swizzled 16B units
__global__ __launch_bounds__(256) void xprep_k(const float* __restrict__ content,
                                               const float* __restrict__ style,
                                               bf16* __restrict__ xg) {
  const int blk = blockIdx.x;  // ((b*128+h)*8+cc), 16384 blocks
  const int cc = blk & 7, h = (blk >> 3) & 127, b = blk >> 10;
  const int x = threadIdx.x & 127, gp = threadIdx.x >> 7;
  bf16* dst = xg + (size_t)blk * 4096;
#pragma unroll
  for (int gg = 0; gg < 2; ++gg) {
    const int g = gp * 2 + gg;
    const int ci0 = cc * 32 + g * 8;
    const float* src = content + ((size_t)(b * 256 + ci0)) * 16384 + h * 128 + x;
    const float* st = style + b * 256 + ci0;
    bf16x8 v;
#pragma unroll
    for (int e = 0; e < 8; ++e) v[e] = (bf16)(src[(size_t)e * 16384] * st[e]);
    *(bf16x8*)(dst + x * 32 + 8 * ((g + ((x + 1) >> 1)) & 3)) = v;
  }
}

// ---------------- main conv: block = M=256 out-ch x N=256 (2 rows), 16 waves
// XG=1: X staged from xg via global_load_lds. XG=0: in-kernel modulate staging.
template <int XG>
__global__ __launch_bounds__(1024, 4) void conv_t(const bf16* __restrict__ xg,
                                                  const float* __restrict__ content,
                                                  const float* __restrict__ style,
                                                  const float* __restrict__ noise,
                                                  const float* __restrict__ bias,
                                                  const float* __restrict__ nwp,
                                                  const float* __restrict__ demod,
                                                  const bf16* __restrict__ wp,
                                                  float* __restrict__ out) {
  // ldsA: dbuf [2][3072 16B-units] = 98304 B.
  // ldsX (XG=1): [4 rows][130 slots x 32 ci] bf16 = 33280 B, swizzled.
  // ldsX (XG=0): [4 rows][130][44] bf16 = 45760 B (stride-88B, 2-way reads).
  constexpr int XROW = XG ? 4160 : 5720;  // bf16 per row area
  __shared__ __align__(16) char smem[98304 + (XG ? 33280 : 45760)];
  bf16* ldsA = (bf16*)smem;
  bf16* ldsX = (bf16*)(smem + 98304);

  const int tid = threadIdx.x;
  const int lane = tid & 63, wv = tid >> 6;      // 16 waves
  const int bid = blockIdx.x;
  const int sp = ((bid & 7) << 7) | (bid >> 3);  // chunked XCD swizzle, bijective
  const int band = sp & 63, b = sp >> 6;
  const int h0 = band * 2;                       // output rows h0, h0+1
  const int g = lane >> 4, nl = lane & 15;
  const int m0 = (wv & 3) * 64;                  // 4 m-tiles -> M=256
  const int nseg = wv >> 2;
  const int rr = nseg >> 1;                      // output row within band (0/1)
  const int x0 = (nseg & 1) * 64;                // 64-px column half

  f32x4 acc[4][4];
  const f32x4 zero4 = {0.f, 0.f, 0.f, 0.f};
#pragma unroll
  for (int mb = 0; mb < 4; ++mb)
#pragma unroll
    for (int nb = 0; nb < 4; ++nb) acc[mb][nb] = zero4;

  const bf16 bz = (bf16)0.f;
  const bf16x8 z8 = {bz, bz, bz, bz, bz, bz, bz, bz};

  // ---- stage A tile (kh,cc) into buffer `buf` (async, drained at next barrier)
  auto stageA = [&](int kh, int cc, int buf) {
    const bf16* seg = wp + (size_t)(kh * 8 + cc) * 24576;
    bf16* dstA = ldsA + buf * 24576;
#pragma unroll
    for (int i = 0; i < 3; ++i) {
      const int u = tid + i * 1024;  // 16B units 0..3071
      __builtin_amdgcn_global_load_lds((const GLOBAL_AS void*)(seg + u * 8),
                                       (LDS_AS void*)(dstA + u * 8), 16, 0, 0);
    }
  };

  // ---- stage X for chunk cc: 4 input rows h0-1..h0+2
  auto stageX = [&](int cc) {
    if constexpr (XG) {
#pragma unroll
      for (int j = 0; j < 2; ++j) {
        const int u = tid + j * 1024;  // 2048 16B-units (512/row)
        const int r = u >> 9;
        const int gh = h0 - 1 + r;
        bf16* dst = ldsX + r * XROW + 32 + (u & 511) * 8;
        if (gh >= 0 && gh < 128) {
          const bf16* src = xg + (size_t)(((b * 128 + gh) << 3) + cc) * 4096 + (u & 511) * 8;
          __builtin_amdgcn_global_load_lds((const GLOBAL_AS void*)src, (LDS_AS void*)dst, 16,
                                           0, 0);
        } else {
          *(bf16x8*)dst = z8;
        }
      }
      if (tid < 32) {  // halo columns pos1=0 and pos1=129: zeros
        const int r = tid >> 3, hw = (tid >> 2) & 1, un = tid & 3;
        *(bf16x8*)(ldsX + r * XROW + (hw ? 4128 : 0) + un * 8) = z8;
      }
    } else {
      const int wS = tid & 127, grp = tid >> 7;
      const int c0 = cc * 32 + grp * 4;
      const float s0 = style[b * 256 + c0 + 0];
      const float s1 = style[b * 256 + c0 + 1];
      const float s2 = style[b * 256 + c0 + 2];
      const float s3 = style[b * 256 + c0 + 3];
      const float* srcb = content + ((size_t)b * 256) * 16384;
#pragma unroll
      for (int r = 0; r < 4; ++r) {
        const int gh = h0 - 1 + r;
        bf16x4 pk = {bz, bz, bz, bz};
        if (gh >= 0 && gh < 128) {
          const float* src = srcb + (size_t)c0 * 16384 + gh * 128 + wS;
          pk[0] = (bf16)(src[0] * s0);
          pk[1] = (bf16)(src[16384] * s1);
          pk[2] = (bf16)(src[2 * 16384] * s2);
          pk[3] = (bf16)(src[3 * 16384] * s3);
        }
        *(bf16x4*)(ldsX + (r * 130 + wS + 1) * 44 + grp * 4) = pk;
      }
      if (tid < 64) {  // halo columns
        const int r = tid >> 4, xh = ((tid >> 3) & 1) ? 129 : 0, q = tid & 7;
        bf16x4 zz = {bz, bz, bz, bz};
        *(bf16x4*)(ldsX + (r * 130 + xh) * 44 + q * 4) = zz;
      }
    }
  };

  // ---- prologue
  stageX(0);
  stageA(0, 0, 0);
  __syncthreads();

  int cur = 0;
  for (int cc = 0; cc < 8; ++cc) {
    for (int kh = 0; kh < 3; ++kh) {
      const int ncc = (kh == 2) ? cc + 1 : cc;
      const int nkh = (kh == 2) ? 0 : kh + 1;
      if (ncc < 8) stageA(nkh, ncc, cur ^ 1);  // prefetch next A (overlaps MFMA)
      const bf16* Ab = ldsA + cur * 24576;
      const int xr = rr + kh;
#pragma unroll
      for (int kw = 0; kw < 3; ++kw) {
        bf16x8 af[4], xf[4];
#pragma unroll
        for (int mb = 0; mb < 4; ++mb)
          af[mb] = *(const bf16x8*)(Ab + ((kw * 4 + g) * 256 + m0 + mb * 16 + nl) * 8);
#pragma unroll
        for (int nb = 0; nb < 4; ++nb) {
          const int p1 = x0 + nb * 16 + nl + kw;  // staged slot index 0..129
          if constexpr (XG)
            xf[nb] = *(const bf16x8*)(ldsX + xr * XROW + p1 * 32 + 8 * ((g + (p1 >> 1)) & 3));
          else
            xf[nb] = *(const bf16x8*)(ldsX + (xr * 130 + p1) * 44 + g * 8);
        }
#pragma unroll
        for (int mb = 0; mb < 4; ++mb)
#pragma unroll
          for (int nb = 0; nb < 4; ++nb)
            acc[mb][nb] =
                __builtin_amdgcn_mfma_f32_16x16x32_bf16(af[mb], xf[nb], acc[mb][nb], 0, 0, 0);
      }
      cur ^= 1;
      __syncthreads();  // drains A prefetch, protects buffers
    }
    if (cc < 7) {
      stageX(cc + 1);   // async (XG) / direct (fallback)
      __syncthreads();  // drains X stage
    }
  }

  // ---- epilogue: demod, noise, bias, leaky_relu(0.2) * sqrt(2)
  const float nw = nwp[0];
  const int hr = h0 + rr;
#pragma unroll
  for (int mb = 0; mb < 4; ++mb) {
    const int o = m0 + mb * 16 + g * 4;  // D row = 4*(lane>>4)+reg
    const f32x4 dm = *(const f32x4*)(demod + b * 256 + o);
    const f32x4 bs = *(const f32x4*)(bias + o);
#pragma unroll
    for (int nb = 0; nb < 4; ++nb) {
      const int x = x0 + nb * 16 + nl;  // D col = lane&15
      const float nz = nw * noise[b * 16384 + hr * 128 + x];
      float* op = out + ((size_t)(b * 256 + o)) * 16384 + hr * 128 + x;
#pragma unroll
      for (int r = 0; r < 4; ++r) {
        float y = acc[mb][nb][r] * dm[r] + nz + bs[r];
        y = (y > 0.f ? y : 0.2f * y) * 1.41421356237f;
        op[(size_t)r * 16384] = y;
      }
    }
  }
}

extern "C" void kernel_launch(void* const* d_in, const int* in_sizes, int n_in,
                              void* d_out, int out_size, void* d_ws, size_t ws_size,
                              hipStream_t stream) {
  const float* content = (const float*)d_in[0];
  const float* latent = (const float*)d_in[1];
  const float* noise = (const float*)d_in[2];
  const float* aff_w = (const float*)d_in[3];
  const float* aff_b = (const float*)d_in[4];
  const float* conv_w = (const float*)d_in[5];
  const float* bias = (const float*)d_in[6];
  const float* nw = (const float*)d_in[7];
  float* out = (float*)d_out;

  float* style = (float*)d_ws;                     // 16*256 fp32
  float* demod = style + 4096;                     // 16*256 fp32
  bf16* wp = (bf16*)((char*)d_ws + 32768);         // 589824 bf16 (1.125 MB)
  bf16* xg = (bf16*)((char*)d_ws + 1212416);       // 16384 * 8KB = 128 MB
  const size_t need = 1212416 + (size_t)16384 * 8192;

  style_k<<<1024, 256, 0, stream>>>(latent, aff_w, aff_b, style);
  demod_k<<<256, 256, 0, stream>>>(conv_w, style, demod);
  wprep_k<<<2304, 256, 0, stream>>>(conv_w, wp);
  if (ws_size >= need) {
    xprep_k<<<16384, 256, 0, stream>>>(content, style, xg);
    conv_t<1><<<1024, 1024, 0, stream>>>(xg, content, style, noise, bias, nw, demod, wp, out);
  } else {
    conv_t<0><<<1024, 1024, 0, stream>>>(nullptr, content, style, noise, bias, nw, demod, wp,
                                         out);
  }
}